// Round 1
// baseline (98.584 us; speedup 1.0000x reference)
//
#include <hip/hip_runtime.h>
#include <math.h>

#define HDIM 128
#define WDIM 128
#define CDIM 64
#define BDIM 4

#define TILE_W 16
#define TILE_H 8
#define HALO_W 20
#define HALO_H 12
#define NPX (HALO_W * HALO_H)     // 240 halo px
#define PSTRIDE 68                // crs pixel stride (16B-aligned, 4 mod 32)
#define WSTRIDE 65                // W LDS stride

typedef short bf16x8 __attribute__((ext_vector_type(8)));
typedef float f32x4  __attribute__((ext_vector_type(4)));

// exact fp32 -> bf16 hi/lo split (3-product emulation, |err| ~ 2^-14)
__device__ __forceinline__ void split_bf16(float f, short& hi, short& lo) {
    unsigned u = __float_as_uint(f);
    hi = (short)(u >> 16);
    float hf = __uint_as_float(u & 0xffff0000u);
    float l  = f - hf;
    lo = (short)(__float_as_uint(l) >> 16);
}

// ---------------------------------------------------------------------------
// Round 10 (this session): 2-kernel split via workspace.
//   Prior fused kernel (89.9 us total) was latency-bound: ~34 us block serial
//   chain, 2 blk/CU, 1 generation, all pipes <20%. Ledger r10-r13 exhausted
//   in-place structural axes. Split attacks the latency slack directly:
//   K1 = cm/cr projection GEMMs to ws (1 barrier, 33 KB LDS, BW-bound);
//   K2 = halo stage from ws + proven scores/softmax (LDS-throughput-bound).
//   cm/cr math identical to fused version -> bit-identical output.
// ---------------------------------------------------------------------------

// ============ K1: cm = xm*Wm, cr = xr*Wr for all pixels -> workspace ========
__global__ __launch_bounds__(256, 1)
void k1_proj(const float* __restrict__ xm, const float* __restrict__ xr,
             const float* __restrict__ Wm, const float* __restrict__ Wr,
             float* __restrict__ cm, float* __restrict__ cr) {
    __shared__ float Wsh[2][64 * WSTRIDE];   // 33,280 B

    const int t    = threadIdx.x;
    const int lane = t & 63;
    const int wv   = t >> 6;
    const int m    = lane & 15;
    const int quad = lane >> 4;
    const int tx0  = blockIdx.x * TILE_W;
    const int ty0  = blockIdx.y * TILE_H;
    const int b    = blockIdx.z;

    // stage both weight matrices once (scalar, stride 65)
    #pragma unroll
    for (int i = 0; i < 16; ++i) {
        int L = t + 256 * i;                 // wave-aligned rows
        int r = L >> 6, c = L & 63;
        Wsh[0][r * WSTRIDE + c] = Wm[L];
        Wsh[1][r * WSTRIDE + c] = Wr[L];
    }
    __syncthreads();                         // only barrier in K1

    #pragma unroll 1                         // keep one B-frag set live
    for (int w = 0; w < 2; ++w) {
        const float* __restrict__ src = w ? xr : xm;
        float* __restrict__ dst       = w ? cr : cm;

        // B frags: B[k=ks*32+quad*8+j][n=nt*16+m]
        bf16x8 Bhi[2][4], Blo[2][4];
        #pragma unroll
        for (int ks = 0; ks < 2; ++ks)
            #pragma unroll
            for (int nt = 0; nt < 4; ++nt)
                #pragma unroll
                for (int j = 0; j < 8; ++j) {
                    float f = Wsh[w][(ks * 32 + quad * 8 + j) * WSTRIDE + nt * 16 + m];
                    short hi, lo; split_bf16(f, hi, lo);
                    Bhi[ks][nt][j] = hi; Blo[ks][nt][j] = lo;
                }

        // 8 M-tiles (rows of the 16x8 tile), 2 per wave
        #pragma unroll
        for (int s = 0; s < 2; ++s) {
            const int tile = 2 * wv + s;     // image row ty0+tile
            const float* ap = src + (((size_t)b * HDIM + ty0 + tile) * WDIM
                                     + tx0 + m) * CDIM + quad * 8;
            float4 p0 = *(const float4*)(ap);
            float4 p1 = *(const float4*)(ap + 4);
            float4 p2 = *(const float4*)(ap + 32);
            float4 p3 = *(const float4*)(ap + 36);

            bf16x8 Ahi[2], Alo[2];
            {
                float fv[16] = {p0.x,p0.y,p0.z,p0.w, p1.x,p1.y,p1.z,p1.w,
                                p2.x,p2.y,p2.z,p2.w, p3.x,p3.y,p3.z,p3.w};
                #pragma unroll
                for (int ks = 0; ks < 2; ++ks)
                    #pragma unroll
                    for (int j = 0; j < 8; ++j) {
                        short hi, lo; split_bf16(fv[8 * ks + j], hi, lo);
                        Ahi[ks][j] = hi; Alo[ks][j] = lo;
                    }
            }
            f32x4 acc[4];
            #pragma unroll
            for (int nt = 0; nt < 4; ++nt)
                { acc[nt][0]=0.f; acc[nt][1]=0.f; acc[nt][2]=0.f; acc[nt][3]=0.f; }
            #pragma unroll
            for (int ks = 0; ks < 2; ++ks)
                #pragma unroll
                for (int nt = 0; nt < 4; ++nt) {
                    acc[nt] = __builtin_amdgcn_mfma_f32_16x16x32_bf16(Ahi[ks], Bhi[ks][nt], acc[nt], 0,0,0);
                    acc[nt] = __builtin_amdgcn_mfma_f32_16x16x32_bf16(Ahi[ks], Blo[ks][nt], acc[nt], 0,0,0);
                    acc[nt] = __builtin_amdgcn_mfma_f32_16x16x32_bf16(Alo[ks], Bhi[ks][nt], acc[nt], 0,0,0);
                }
            // D: pixel x = tx0 + quad*4 + r, channel = nt*16 + m
            // per (nt,r) store: 4 px x 16 consecutive ch floats = 64 B chunks
            #pragma unroll
            for (int nt = 0; nt < 4; ++nt)
                #pragma unroll
                for (int r = 0; r < 4; ++r)
                    dst[(((size_t)b * HDIM + ty0 + tile) * WDIM
                         + tx0 + quad * 4 + r) * CDIM + nt * 16 + m] = acc[nt][r];
        }
    }
}

// ============ K2: halo stage from ws + scores + softmax =====================
__global__ __launch_bounds__(256, 1)
void k2_scores(const float* __restrict__ cm, const float* __restrict__ cr,
               float* __restrict__ out) {
    __shared__ float crs[NPX * PSTRIDE];     // 65,280 B -> 2 blk/CU

    const int t   = threadIdx.x;
    const int tx0 = blockIdx.x * TILE_W;
    const int ty0 = blockIdx.y * TILE_H;
    const int b   = blockIdx.z;

    // stage cr halo: 240 px x 16 float4 slots = 3840, 15 per thread, OOB -> 0
    #pragma unroll
    for (int i = 0; i < 15; ++i) {
        int L  = t + 256 * i;
        int p  = L >> 4, sl = L & 15;
        int hy = p / HALO_W, hx = p - hy * HALO_W;
        int gy = ty0 + hy - 2, gx = tx0 + hx - 2;
        float4 v = make_float4(0.f, 0.f, 0.f, 0.f);
        if (gy >= 0 && gy < HDIM && gx >= 0 && gx < WDIM)
            v = *(const float4*)&cr[(((size_t)b * HDIM + gy) * WDIM + gx) * CDIM + sl * 4];
        *(float4*)&crs[p * PSTRIDE + sl * 4] = v;
    }

    // qv straight from global cm (coalesced, independent of crs -> pre-barrier)
    const int pl = t >> 1;
    const int cg = t & 1;
    const int lx = pl & (TILE_W - 1);
    const int ly = pl >> 4;
    const size_t gpx = ((size_t)b * HDIM + ty0 + ly) * WDIM + tx0 + lx;
    float4 qv[8];
    #pragma unroll
    for (int mq = 0; mq < 8; ++mq)
        qv[mq] = *(const float4*)&cm[gpx * CDIM + cg * 32 + 4 * mq];
    __syncthreads();

    // scores (proven phase-5 body, verbatim)
    float s[26];
    #pragma unroll
    for (int k = 0; k < 25; ++k) {
        const int i = k / 5, j = k % 5;
        const int p = (ly + i) * HALO_W + (lx + j);
        const float4* kp = (const float4*)&crs[p * PSTRIDE + cg * 32];
        float acc = 0.f;
        #pragma unroll
        for (int mq = 0; mq < 8; ++mq) {
            float4 v = kp[mq];
            acc = fmaf(qv[mq].x, v.x, acc);
            acc = fmaf(qv[mq].y, v.y, acc);
            acc = fmaf(qv[mq].z, v.z, acc);
            acc = fmaf(qv[mq].w, v.w, acc);
        }
        s[k] = acc;
    }
    {
        float acc = 0.f;
        #pragma unroll
        for (int mq = 0; mq < 8; ++mq) {
            float4 v = qv[mq];
            acc = fmaf(v.x, v.x, acc);
            acc = fmaf(v.y, v.y, acc);
            acc = fmaf(v.z, v.z, acc);
            acc = fmaf(v.w, v.w, acc);
        }
        s[25] = acc;
    }

    #pragma unroll
    for (int k = 0; k < 26; ++k) s[k] += __shfl_xor(s[k], 1);

    float mx = s[0];
    #pragma unroll
    for (int k = 1; k < 26; ++k) mx = fmaxf(mx, s[k]);
    float sum = 0.f;
    #pragma unroll
    for (int k = 0; k < 26; ++k) { s[k] = __expf(s[k] - mx); sum += s[k]; }
    const float inv = 1.f / sum;

    float* op = &out[gpx * 26 + cg * 13];
    if (cg == 0) {
        #pragma unroll
        for (int k = 0; k < 13; ++k) op[k] = s[k] * inv;
    } else {
        #pragma unroll
        for (int k = 0; k < 13; ++k) op[k] = s[13 + k] * inv;
    }
}

// ---------------------------------------------------------------------------
extern "C" void kernel_launch(void* const* d_in, const int* in_sizes, int n_in,
                              void* d_out, int out_size, void* d_ws, size_t ws_size,
                              hipStream_t stream) {
    const float* xm = (const float*)d_in[0];
    const float* xr = (const float*)d_in[1];
    const float* Wm = (const float*)d_in[2];
    const float* Wr = (const float*)d_in[3];
    float* outp = (float*)d_out;

    // workspace layout: cm [4*128*128*64] f32 | cr [4*128*128*64] f32 = 33.6 MB
    float* cmw = (float*)d_ws;
    float* crw = cmw + (size_t)BDIM * HDIM * WDIM * CDIM;

    dim3 g(WDIM / TILE_W, HDIM / TILE_H, BDIM);   // 8 x 16 x 4 = 512 blocks
    k1_proj<<<g, 256, 0, stream>>>(xm, xr, Wm, Wr, cmw, crw);
    k2_scores<<<g, 256, 0, stream>>>(cmw, crw, outp);
}

// Round 2
// 88.995 us; speedup vs baseline: 1.1077x; 1.1077x over previous
//
#include <hip/hip_runtime.h>
#include <math.h>

#define HDIM 128
#define WDIM 128
#define CDIM 64
#define BDIM 4

#define TILE_W 16
#define TILE_H 8
#define HALO_W 20
#define HALO_H 12
#define NHALO (HALO_W * HALO_H)   // 240 halo px = 15 M-tiles of 16
#define PSTRIDE 68                // cm/crs pixel stride (16B-aligned, 4 mod 32)
#define WSTRIDE 65                // W LDS stride (2-way banks on frag reads)

typedef short bf16x8 __attribute__((ext_vector_type(8)));
typedef float f32x4  __attribute__((ext_vector_type(4)));

// exact fp32 -> bf16 hi/lo split (3-product emulation, |err| ~ 2^-14)
__device__ __forceinline__ void split_bf16(float f, short& hi, short& lo) {
    unsigned u = __float_as_uint(f);
    hi = (short)(u >> 16);
    float hf = __uint_as_float(u & 0xffff0000u);
    float l  = f - hf;
    lo = (short)(__float_as_uint(l) >> 16);
}

// ---------------------------------------------------------------------------
// Fused MFMA local-attn — RESTORED round-9 kernel (measured best: 89.9-90.0 us).
//   Exploration ledger (r10-r14): hoisted prefetch 91.0; 2-barrier/global-W
//   91.8; 16x4 VGPR-capped spill 119.9; 8x8 4-blk/CU 2-gen 94.7; 2-kernel
//   ws split (K1 proj -> ws, K2 halo+scores) 98.6 -- ws round-trip prices at
//   HBM rate (~10.6 us for 67 MB), NOT L3, because the 268 MB ws poison fill
//   leaves L3 full of dirty poison lines. Six structural axes all lose to r9
//   by their own mechanism -> kernel is at a ~34 us latency floor (HBM floor
//   ~10 us, scores-LDS ~8 us, all pipes <20% busy at the 2-blk/CU occupancy
//   the 65,280 B LDS permits); fixed harness work (268 MB ws fill ~43.5 us +
//   input restores + out poison) ~56 us dominates dur_us.
//   Structure: per 16x8 tile — stage Wm->LDS, Bm frags; cm GEMM (split-bf16
//   3-product MFMA, A-frags direct from global); cm->LDS, qv extract;
//   restage Wr, Br frags; cr halo GEMM (240 px, 15 M-tiles); scores+softmax.
//   LDS multiplex: Wsh[0..4160) | cms[4352..13056) | crs[0..16320).
// ---------------------------------------------------------------------------
__global__ __launch_bounds__(256, 1)
void fused_mfma_local_attn(const float* __restrict__ xm,
                           const float* __restrict__ xr,
                           const float* __restrict__ Wm,
                           const float* __restrict__ Wr,
                           float* __restrict__ out) {
    __shared__ float lds[16320];        // 65,280 B
    float* Wsh = lds;                   // [64][65]
    float* cms = lds + 4352;            // [128][68]
    float* crs = lds;                   // [240][68]

    const int t    = threadIdx.x;
    const int lane = t & 63;
    const int wv   = t >> 6;
    const int m    = lane & 15;
    const int quad = lane >> 4;
    const int tx0  = blockIdx.x * TILE_W;
    const int ty0  = blockIdx.y * TILE_H;
    const int b    = blockIdx.z;

    // ============ phase 1: stage Wm (scalar, stride 65) ============
    #pragma unroll
    for (int i = 0; i < 16; ++i) {
        int L = t + 256 * i;            // wave-aligned: k = L>>6 uniform/wave
        Wsh[(L >> 6) * WSTRIDE + (L & 63)] = Wm[L];
    }
    __syncthreads();

    // build Bm frags: B[k=ks*32+quad*8+j][n=nt*16+m]
    bf16x8 Bhi[2][4], Blo[2][4];
    #pragma unroll
    for (int ks = 0; ks < 2; ++ks)
        #pragma unroll
        for (int nt = 0; nt < 4; ++nt)
            #pragma unroll
            for (int j = 0; j < 8; ++j) {
                float f = Wsh[(ks * 32 + quad * 8 + j) * WSTRIDE + nt * 16 + m];
                short hi, lo; split_bf16(f, hi, lo);
                Bhi[ks][nt][j] = hi; Blo[ks][nt][j] = lo;
            }

    // ============ phase 2: cm GEMM — 2 M-tiles (rows) per wave ============
    #pragma unroll
    for (int s = 0; s < 2; ++s) {
        const int tile = 2 * wv + s;                 // row ty0+tile
        const float* ap = xm + (((size_t)b * HDIM + ty0 + tile) * WDIM
                                + tx0 + m) * CDIM + quad * 8;
        float4 p0 = *(const float4*)(ap);
        float4 p1 = *(const float4*)(ap + 4);
        float4 p2 = *(const float4*)(ap + 32);
        float4 p3 = *(const float4*)(ap + 36);

        bf16x8 Ahi[2], Alo[2];
        {
            float fv[16] = {p0.x,p0.y,p0.z,p0.w, p1.x,p1.y,p1.z,p1.w,
                            p2.x,p2.y,p2.z,p2.w, p3.x,p3.y,p3.z,p3.w};
            #pragma unroll
            for (int ks = 0; ks < 2; ++ks)
                #pragma unroll
                for (int j = 0; j < 8; ++j) {
                    short hi, lo; split_bf16(fv[8 * ks + j], hi, lo);
                    Ahi[ks][j] = hi; Alo[ks][j] = lo;
                }
        }
        f32x4 acc[4];
        #pragma unroll
        for (int nt = 0; nt < 4; ++nt)
            { acc[nt][0]=0.f; acc[nt][1]=0.f; acc[nt][2]=0.f; acc[nt][3]=0.f; }
        #pragma unroll
        for (int ks = 0; ks < 2; ++ks)
            #pragma unroll
            for (int nt = 0; nt < 4; ++nt) {
                acc[nt] = __builtin_amdgcn_mfma_f32_16x16x32_bf16(Ahi[ks], Bhi[ks][nt], acc[nt], 0,0,0);
                acc[nt] = __builtin_amdgcn_mfma_f32_16x16x32_bf16(Ahi[ks], Blo[ks][nt], acc[nt], 0,0,0);
                acc[nt] = __builtin_amdgcn_mfma_f32_16x16x32_bf16(Alo[ks], Bhi[ks][nt], acc[nt], 0,0,0);
            }
        // D: pixel-in-tile = quad*4+r, channel = nt*16+m
        #pragma unroll
        for (int nt = 0; nt < 4; ++nt)
            #pragma unroll
            for (int r = 0; r < 4; ++r)
                cms[(tile * 16 + quad * 4 + r) * PSTRIDE + nt * 16 + m] = acc[nt][r];
    }
    __syncthreads();   // B2: Wsh(Wm) reads + cms writes done

    // ============ phase 3: stage Wr, build Br, extract qv ============
    #pragma unroll
    for (int i = 0; i < 16; ++i) {
        int L = t + 256 * i;
        Wsh[(L >> 6) * WSTRIDE + (L & 63)] = Wr[L];
    }
    __syncthreads();                    // B3

    #pragma unroll
    for (int ks = 0; ks < 2; ++ks)
        #pragma unroll
        for (int nt = 0; nt < 4; ++nt)
            #pragma unroll
            for (int j = 0; j < 8; ++j) {
                float f = Wsh[(ks * 32 + quad * 8 + j) * WSTRIDE + nt * 16 + m];
                short hi, lo; split_bf16(f, hi, lo);
                Bhi[ks][nt][j] = hi; Blo[ks][nt][j] = lo;
            }

    const int pl = t >> 1;
    const int cg = t & 1;
    float4 qv[8];
    #pragma unroll
    for (int mq = 0; mq < 8; ++mq)
        qv[mq] = *(const float4*)&cms[pl * PSTRIDE + cg * 32 + 4 * mq];
    __syncthreads();                    // B4: Wsh/cms reads done before crs

    // ============ phase 4: cr halo GEMM (15 M-tiles over 4 waves) ============
    #pragma unroll
    for (int s = 0; s < 4; ++s) {
        const int tj = wv + 4 * s;
        if (tj < 15) {
            const int hp = tj * 16 + m;
            const int hy = hp / HALO_W;
            const int hx = hp - hy * HALO_W;
            const int gy = ty0 + hy - 2, gx = tx0 + hx - 2;
            float4 p0 = make_float4(0,0,0,0), p1 = p0, p2 = p0, p3 = p0;
            if (gy >= 0 && gy < HDIM && gx >= 0 && gx < WDIM) {
                const float* ap = xr + (((size_t)b * HDIM + gy) * WDIM + gx) * CDIM
                                  + quad * 8;
                p0 = *(const float4*)(ap);
                p1 = *(const float4*)(ap + 4);
                p2 = *(const float4*)(ap + 32);
                p3 = *(const float4*)(ap + 36);
            }
            bf16x8 Ahi[2], Alo[2];
            {
                float fv[16] = {p0.x,p0.y,p0.z,p0.w, p1.x,p1.y,p1.z,p1.w,
                                p2.x,p2.y,p2.z,p2.w, p3.x,p3.y,p3.z,p3.w};
                #pragma unroll
                for (int ks = 0; ks < 2; ++ks)
                    #pragma unroll
                    for (int j = 0; j < 8; ++j) {
                        short hi, lo; split_bf16(fv[8 * ks + j], hi, lo);
                        Ahi[ks][j] = hi; Alo[ks][j] = lo;
                    }
            }
            f32x4 acc[4];
            #pragma unroll
            for (int nt = 0; nt < 4; ++nt)
                { acc[nt][0]=0.f; acc[nt][1]=0.f; acc[nt][2]=0.f; acc[nt][3]=0.f; }
            #pragma unroll
            for (int ks = 0; ks < 2; ++ks)
                #pragma unroll
                for (int nt = 0; nt < 4; ++nt) {
                    acc[nt] = __builtin_amdgcn_mfma_f32_16x16x32_bf16(Ahi[ks], Bhi[ks][nt], acc[nt], 0,0,0);
                    acc[nt] = __builtin_amdgcn_mfma_f32_16x16x32_bf16(Ahi[ks], Blo[ks][nt], acc[nt], 0,0,0);
                    acc[nt] = __builtin_amdgcn_mfma_f32_16x16x32_bf16(Alo[ks], Bhi[ks][nt], acc[nt], 0,0,0);
                }
            #pragma unroll
            for (int nt = 0; nt < 4; ++nt)
                #pragma unroll
                for (int r = 0; r < 4; ++r)
                    crs[(tj * 16 + quad * 4 + r) * PSTRIDE + nt * 16 + m] = acc[nt][r];
        }
    }
    __syncthreads();                    // B5

    // ============ phase 5: scores + softmax (proven) ============
    const int lx = pl & (TILE_W - 1);
    const int ly = pl >> 4;
    const size_t gpx = ((size_t)b * HDIM + ty0 + ly) * WDIM + tx0 + lx;

    float s[26];
    #pragma unroll
    for (int k = 0; k < 25; ++k) {
        const int i = k / 5, j = k % 5;
        const int p = (ly + i) * HALO_W + (lx + j);
        const float4* kp = (const float4*)&crs[p * PSTRIDE + cg * 32];
        float acc = 0.f;
        #pragma unroll
        for (int mq = 0; mq < 8; ++mq) {
            float4 v = kp[mq];
            acc = fmaf(qv[mq].x, v.x, acc);
            acc = fmaf(qv[mq].y, v.y, acc);
            acc = fmaf(qv[mq].z, v.z, acc);
            acc = fmaf(qv[mq].w, v.w, acc);
        }
        s[k] = acc;
    }
    {
        float acc = 0.f;
        #pragma unroll
        for (int mq = 0; mq < 8; ++mq) {
            float4 v = qv[mq];
            acc = fmaf(v.x, v.x, acc);
            acc = fmaf(v.y, v.y, acc);
            acc = fmaf(v.z, v.z, acc);
            acc = fmaf(v.w, v.w, acc);
        }
        s[25] = acc;
    }

    #pragma unroll
    for (int k = 0; k < 26; ++k) s[k] += __shfl_xor(s[k], 1);

    float mx = s[0];
    #pragma unroll
    for (int k = 1; k < 26; ++k) mx = fmaxf(mx, s[k]);
    float sum = 0.f;
    #pragma unroll
    for (int k = 0; k < 26; ++k) { s[k] = __expf(s[k] - mx); sum += s[k]; }
    const float inv = 1.f / sum;

    float* op = &out[gpx * 26 + cg * 13];
    if (cg == 0) {
        #pragma unroll
        for (int k = 0; k < 13; ++k) op[k] = s[k] * inv;
    } else {
        #pragma unroll
        for (int k = 0; k < 13; ++k) op[k] = s[13 + k] * inv;
    }
}

// ---------------------------------------------------------------------------
extern "C" void kernel_launch(void* const* d_in, const int* in_sizes, int n_in,
                              void* d_out, int out_size, void* d_ws, size_t ws_size,
                              hipStream_t stream) {
    const float* xm = (const float*)d_in[0];
    const float* xr = (const float*)d_in[1];
    const float* Wm = (const float*)d_in[2];
    const float* Wr = (const float*)d_in[3];
    float* outp = (float*)d_out;

    dim3 g(WDIM / TILE_W, HDIM / TILE_H, BDIM);   // 8 x 16 x 4 = 512 blocks
    fused_mfma_local_attn<<<g, 256, 0, stream>>>(xm, xr, Wm, Wr, outp);
}